// Round 9
// baseline (1393.251 us; speedup 1.0000x reference)
//
#include <hip/hip_runtime.h>
#include <math.h>

#define T_STEPS 24
#define F_IN 10
#define HDIM 128
#define E_EDGES 80000
#define B_BATCH 8
#define N_NODES 5000
#define BN_TOTAL 40000
#define BE 640000
#define NE 680000

typedef __attribute__((ext_vector_type(8))) short s16x8;
typedef __attribute__((ext_vector_type(4))) short s16x4;
typedef __attribute__((ext_vector_type(4))) float fx4;
typedef __attribute__((ext_vector_type(2))) float fx2;
typedef __attribute__((ext_vector_type(4))) unsigned int ux4;
typedef __attribute__((ext_vector_type(2))) unsigned int ux2;

__device__ __forceinline__ float sigmoidf_(float v) { return 1.f / (1.f + __expf(-v)); }
__device__ __forceinline__ float tanhf_(float v) { float e = __expf(2.f * v); return 1.f - 2.f / (e + 1.f); }

__device__ __forceinline__ short f2b(float f) {
    unsigned u = __float_as_uint(f);
    unsigned r = (u + 0x7fffu + ((u >> 16) & 1u)) >> 16;
    return (short)r;
}
__device__ __forceinline__ unsigned int pkbf(float a, float b) {
    unsigned int r;
    asm("v_cvt_pk_bf16_f32 %0, %1, %2" : "=v"(r) : "v"(a), "v"(b));
    return r;
}
__device__ __forceinline__ float bfu(unsigned short u) {
    return __uint_as_float(((unsigned)u) << 16);
}

// ---------------- pack weights into MFMA A-fragment order (bf16), nf-major ----------------
// shorts: [0,49152) hh0 ; [49152,98304) hh1 ; [98304,147456) ih1 ; [147456,159744) ih0(K pad 10->32)
//         [159744,225280) g1w ; [225280,290816) g2w
__global__ void pack_w(const float* __restrict__ wih0, const float* __restrict__ whh0,
                       const float* __restrict__ wih1, const float* __restrict__ whh1,
                       const float* __restrict__ g1w, const float* __restrict__ g2w,
                       short* __restrict__ pk) {
    int id = blockIdx.x * 256 + threadIdx.x;
    if (id >= 290816) return;
    if (id < 147456) {
        int mat = id / 49152, r = id % 49152;
        int nf = r / 2048, r2 = r % 2048, kf = r2 / 512, r3 = r2 % 512, lane = r3 / 8, j = r3 % 8;
        int n = nf * 16 + (lane & 15), k = kf * 32 + (lane >> 4) * 8 + j;
        const float* src = (mat == 0) ? whh0 : (mat == 1) ? whh1 : wih1;
        pk[id] = f2b(src[n * 128 + k]);
    } else if (id < 159744) {
        int r = id - 147456;
        int nf = r / 512, r2 = r % 512, lane = r2 / 8, j = r2 % 8;
        int n = nf * 16 + (lane & 15), k = (lane >> 4) * 8 + j;
        pk[id] = (k < F_IN) ? f2b(wih0[n * F_IN + k]) : (short)0;
    } else {
        const float* src = (id < 225280) ? g1w : g2w;
        int r = (id < 225280) ? (id - 159744) : (id - 225280);
        int nf = r / 2048, r2 = r % 2048, kf = r2 / 512, r3 = r2 % 512, lane = r3 / 8, j = r3 % 8;
        int n = nf * 16 + (lane & 15), k = kf * 32 + (lane >> 4) * 8 + j;
        pk[id] = f2b(src[n * 128 + k]);
    }
}

// ---------------- fused 2-layer GRU; 64 seqs/block, ALL weights in registers ----------------
// LDS = 36 KB -> 3 blocks/CU (VGPR-limited ~6 waves/SIMD). 625 blocks all co-resident.
__global__ __launch_bounds__(512, 1) void gru_mfma(
    const float* __restrict__ x, const short* __restrict__ pk,
    const float* __restrict__ bih0, const float* __restrict__ bhh0,
    const float* __restrict__ bih1, const float* __restrict__ bhh1,
    float* __restrict__ temporal) {
    __shared__ __align__(16) short h1b[64 * 128];     // 16 KB
    __shared__ __align__(16) short h2b[64 * 128];     // 16 KB
    __shared__ __align__(16) float blds[2][4][128];   // 4 KB
    const int tid = threadIdx.x;
    const int w = tid >> 6, l = tid & 63;
    const int lm = l & 15, lk = l >> 4;
    const int jb = w * 16 + lk * 4;
    const long sb = (long)blockIdx.x * 64;

    if (tid < 128) {
        const int j = tid;
        blds[0][0][j] = bih0[j] + bhh0[j];
        blds[0][1][j] = bih0[128 + j] + bhh0[128 + j];
        blds[0][2][j] = bhh0[256 + j];
        blds[0][3][j] = bih0[256 + j];
    } else if (tid < 256) {
        const int j = tid - 128;
        blds[1][0][j] = bih1[j] + bhh1[j];
        blds[1][1][j] = bih1[128 + j] + bhh1[128 + j];
        blds[1][2][j] = bhh1[256 + j];
        blds[1][3][j] = bih1[256 + j];
    }
    for (int i = tid; i < 64 * 128; i += 512) { h1b[i] = 0; h2b[i] = 0; }

    // ---- ALL weights resident in registers (unified VGPR/AGPR file) ----
    s16x8 whh0r[3][4], whh1r[3][4], wih1r[3][4], wih0r[3];
#pragma unroll
    for (int g = 0; g < 3; ++g) {
#pragma unroll
        for (int kf = 0; kf < 4; ++kf) {
            const int idx = ((((g * 8 + w) * 4) + kf) * 64 + l) * 8;
            whh0r[g][kf] = *(const s16x8*)&pk[idx];
            whh1r[g][kf] = *(const s16x8*)&pk[49152 + idx];
            wih1r[g][kf] = *(const s16x8*)&pk[98304 + idx];
        }
        wih0r[g] = *(const s16x8*)&pk[147456 + ((g * 8 + w) * 64 + l) * 8];
    }

    fx4 h1s[4], h2s[4];
#pragma unroll
    for (int mf = 0; mf < 4; ++mf) { h1s[mf] = (fx4)(0.f); h2s[mf] = (fx4)(0.f); }

    __syncthreads();

    for (int tt = 0; tt < T_STEPS; ++tt) {
        // ---- x loads, converted to bf16 immediately ----
        ux4 xu[4];
#pragma unroll
        for (int mf = 0; mf < 4; ++mf) {
            fx2 a0 = (fx2)(0.f), a1 = (fx2)(0.f), a2 = (fx2)(0.f), a3 = (fx2)(0.f);
            const float* xr = x + (sb + mf * 16 + lm) * (T_STEPS * F_IN) + tt * F_IN;
            if (lk == 0) {
                a0 = *(const fx2*)(xr);     a1 = *(const fx2*)(xr + 2);
                a2 = *(const fx2*)(xr + 4); a3 = *(const fx2*)(xr + 6);
            } else if (lk == 1) {
                a0 = *(const fx2*)(xr + 8);
            }
            ux4 t = { pkbf(a0.x, a0.y), pkbf(a1.x, a1.y), pkbf(a2.x, a2.y), pkbf(a3.x, a3.y) };
            xu[mf] = t;
        }
        fx4 acc[4][4];
#pragma unroll
        for (int p = 0; p < 4; ++p) {
            const fx4 bv = *(const fx4*)&blds[0][p][jb];
#pragma unroll
            for (int mf = 0; mf < 4; ++mf) acc[p][mf] = bv;
        }
        // ===== layer 0: hh0 (B = h1 old), parts r,z,nh =====
#pragma unroll
        for (int kf = 0; kf < 4; ++kf) {
            s16x8 bfr[4];
#pragma unroll
            for (int mf = 0; mf < 4; ++mf) {
                const int m = mf * 16 + lm;
                const int slot = (kf * 4 + lk) ^ (m & 7);
                bfr[mf] = *(const s16x8*)&h1b[m * 128 + slot * 8];
            }
#pragma unroll
            for (int g = 0; g < 3; ++g) {
                const int part = (g == 2) ? 2 : g;
#pragma unroll
                for (int mf = 0; mf < 4; ++mf)
                    acc[part][mf] = __builtin_amdgcn_mfma_f32_16x16x32_bf16(whh0r[g][kf], bfr[mf], acc[part][mf], 0, 0, 0);
            }
        }
        // ---- ih0 (A regs, B = x frags), parts r,z,ni ----
#pragma unroll
        for (int g = 0; g < 3; ++g) {
            const int part = (g == 2) ? 3 : g;
#pragma unroll
            for (int mf = 0; mf < 4; ++mf)
                acc[part][mf] = __builtin_amdgcn_mfma_f32_16x16x32_bf16(wih0r[g], __builtin_bit_cast(s16x8, xu[mf]), acc[part][mf], 0, 0, 0);
        }
        // ---- elementwise layer 0 -> h1 (fp32 state) ----
        ux2 w1[4];
#pragma unroll
        for (int mf = 0; mf < 4; ++mf) {
#pragma unroll
            for (int rg = 0; rg < 4; ++rg) {
                const float r = sigmoidf_(acc[0][mf][rg]);
                const float z = sigmoidf_(acc[1][mf][rg]);
                const float n = tanhf_(acc[3][mf][rg] + r * acc[2][mf][rg]);
                h1s[mf][rg] = (1.f - z) * n + z * h1s[mf][rg];
            }
            ux2 q = { pkbf(h1s[mf][0], h1s[mf][1]), pkbf(h1s[mf][2], h1s[mf][3]) };
            w1[mf] = q;
        }
        // ===== layer 1: hh1 (B = h2 old), parts r,z,nh =====
#pragma unroll
        for (int p = 0; p < 4; ++p) {
            const fx4 bv = *(const fx4*)&blds[1][p][jb];
#pragma unroll
            for (int mf = 0; mf < 4; ++mf) acc[p][mf] = bv;
        }
#pragma unroll
        for (int kf = 0; kf < 4; ++kf) {
            s16x8 bfr[4];
#pragma unroll
            for (int mf = 0; mf < 4; ++mf) {
                const int m = mf * 16 + lm;
                const int slot = (kf * 4 + lk) ^ (m & 7);
                bfr[mf] = *(const s16x8*)&h2b[m * 128 + slot * 8];
            }
#pragma unroll
            for (int g = 0; g < 3; ++g) {
                const int part = (g == 2) ? 2 : g;
#pragma unroll
                for (int mf = 0; mf < 4; ++mf)
                    acc[part][mf] = __builtin_amdgcn_mfma_f32_16x16x32_bf16(whh1r[g][kf], bfr[mf], acc[part][mf], 0, 0, 0);
            }
        }
        __syncthreads();   // all reads of h1b(old)/h2b(old) complete
#pragma unroll
        for (int mf = 0; mf < 4; ++mf) {
            const int m = mf * 16 + lm;
            const int slot = (jb >> 3) ^ (m & 7);
            *(ux2*)&h1b[m * 128 + slot * 8 + (jb & 7)] = w1[mf];
        }
        __syncthreads();   // h1 new visible
        // ===== layer 1: ih1 (A regs, B = h1 new), parts r,z,ni =====
#pragma unroll
        for (int kf = 0; kf < 4; ++kf) {
            s16x8 bfr[4];
#pragma unroll
            for (int mf = 0; mf < 4; ++mf) {
                const int m = mf * 16 + lm;
                const int slot = (kf * 4 + lk) ^ (m & 7);
                bfr[mf] = *(const s16x8*)&h1b[m * 128 + slot * 8];
            }
#pragma unroll
            for (int g = 0; g < 3; ++g) {
                const int part = (g == 2) ? 3 : g;
#pragma unroll
                for (int mf = 0; mf < 4; ++mf)
                    acc[part][mf] = __builtin_amdgcn_mfma_f32_16x16x32_bf16(wih1r[g][kf], bfr[mf], acc[part][mf], 0, 0, 0);
            }
        }
        // ---- elementwise layer 1 -> h2, publish ----
#pragma unroll
        for (int mf = 0; mf < 4; ++mf) {
#pragma unroll
            for (int rg = 0; rg < 4; ++rg) {
                const float r = sigmoidf_(acc[0][mf][rg]);
                const float z = sigmoidf_(acc[1][mf][rg]);
                const float n = tanhf_(acc[3][mf][rg] + r * acc[2][mf][rg]);
                h2s[mf][rg] = (1.f - z) * n + z * h2s[mf][rg];
            }
            const int m = mf * 16 + lm;
            const int slot = (jb >> 3) ^ (m & 7);
            ux2 q = { pkbf(h2s[mf][0], h2s[mf][1]), pkbf(h2s[mf][2], h2s[mf][3]) };
            *(ux2*)&h2b[m * 128 + slot * 8 + (jb & 7)] = q;
        }
        __syncthreads();   // h2 new visible for next step
    }
#pragma unroll
    for (int mf = 0; mf < 4; ++mf) {
        const long m = sb + mf * 16 + lm;
        *(fx4*)&temporal[m * 128 + jb] = h2s[mf];
    }
}

// ---------------- CSR build ----------------
__global__ void csr_count(const int* __restrict__ edge1, int* __restrict__ cnt) {
    int e = blockIdx.x * 256 + threadIdx.x;
    if (e >= NE) return;
    int d;
    if (e < BE) { int b = e / E_EDGES; d = edge1[e - b * E_EDGES] + b * N_NODES; }
    else d = e - BE;
    atomicAdd(&cnt[d], 1);
}

__global__ void csr_scan(const int* cnt, int* offs, int* curs) {
    __shared__ int part[1024];
    const int t = threadIdx.x;
    const int base = t * 40;
    int end = base + 40; if (end > BN_TOTAL) end = BN_TOTAL;
    int s = 0;
    for (int i = base; i < end; ++i) s += cnt[i];
    part[t] = s;
    __syncthreads();
    for (int off = 1; off < 1024; off <<= 1) {
        int v = (t >= off) ? part[t - off] : 0;
        __syncthreads();
        part[t] += v;
        __syncthreads();
    }
    int run = part[t] - s;
    for (int i = base; i < end; ++i) {
        int c = cnt[i];
        offs[i] = run; curs[i] = run; run += c;
    }
    if (t == 1023) offs[BN_TOTAL] = NE;
}

__global__ void csr_fill(const int* __restrict__ edge1, int* __restrict__ curs, int* __restrict__ esort) {
    int e = blockIdx.x * 256 + threadIdx.x;
    if (e >= NE) return;
    int d;
    if (e < BE) { int b = e / E_EDGES; d = edge1[e - b * E_EDGES] + b * N_NODES; }
    else d = e - BE;
    int pos = atomicAdd(&curs[d], 1);
    esort[pos] = e;
}

// ------- GAT: wh = feat @ W.T via MFMA (128 rows x one head per block), bf16 out -------
__global__ __launch_bounds__(256, 2) void gat_gemm(const float* __restrict__ feat,
                                                   const short* __restrict__ pkg,
                                                   const float* __restrict__ asrc,
                                                   const float* __restrict__ adst,
                                                   unsigned short* __restrict__ whb,
                                                   float* __restrict__ AS, float* __restrict__ AD) {
    __shared__ __align__(16) short fb[128 * 128];   // 32 KB bf16, XOR-swizzled
    __shared__ float reda[4][128];
    __shared__ float redb[4][128];
    const int tid = threadIdx.x;
    const int w = tid >> 6, l = tid & 63;
    const int lm = l & 15, lk = l >> 4;
    const int i0 = blockIdx.x * 128;
    const int j0 = blockIdx.y * 128;     // == head*128
#pragma unroll
    for (int it = 0; it < 16; ++it) {
        const int idx = it * 256 + tid;
        const int r = idx >> 5, kq = idx & 31;
        fx4 v = (fx4)(0.f);
        const int row = i0 + r;
        if (row < BN_TOTAL) v = *(const fx4*)&feat[(size_t)row * 128 + kq * 4];
        const int slot = (kq >> 1) ^ (r & 7);
        ux2 pv = { pkbf(v.x, v.y), pkbf(v.z, v.w) };
        *(ux2*)&fb[r * 128 + slot * 8 + (kq & 1) * 4] = pv;
    }
    __syncthreads();
    fx4 acc[2][8];
#pragma unroll
    for (int jf = 0; jf < 2; ++jf)
#pragma unroll
        for (int mf = 0; mf < 8; ++mf) acc[jf][mf] = (fx4)(0.f);
#pragma unroll
    for (int kf = 0; kf < 4; ++kf) {
        s16x8 bfr[8];
#pragma unroll
        for (int mf = 0; mf < 8; ++mf) {
            const int m = mf * 16 + lm;
            const int slot = (kf * 4 + lk) ^ (m & 7);
            bfr[mf] = *(const s16x8*)&fb[m * 128 + slot * 8];
        }
#pragma unroll
        for (int jf = 0; jf < 2; ++jf) {
            const int nf = (j0 >> 4) + w * 2 + jf;
            const s16x8 af = *(const s16x8*)&pkg[((nf * 4 + kf) * 64 + l) * 8];
#pragma unroll
            for (int mf = 0; mf < 8; ++mf)
                acc[jf][mf] = __builtin_amdgcn_mfma_f32_16x16x32_bf16(af, bfr[mf], acc[jf][mf], 0, 0, 0);
        }
    }
    // ---- write wh (bf16) + fused alpha partials (fp32) ----
    float ps[8], pd[8];
#pragma unroll
    for (int mf = 0; mf < 8; ++mf) { ps[mf] = 0.f; pd[mf] = 0.f; }
#pragma unroll
    for (int jf = 0; jf < 2; ++jf) {
        const int cb = w * 32 + jf * 16 + lk * 4;
        const fx4 s4 = *(const fx4*)&asrc[j0 + cb];
        const fx4 d4 = *(const fx4*)&adst[j0 + cb];
        const int nb = j0 + cb;
#pragma unroll
        for (int mf = 0; mf < 8; ++mf) {
            const int m = i0 + mf * 16 + lm;
            const fx4 a = acc[jf][mf];
            if (m < BN_TOTAL) {
                ux2 pv = { pkbf(a.x, a.y), pkbf(a.z, a.w) };
                *(ux2*)&whb[(size_t)m * 512 + nb] = pv;
            }
            ps[mf] += a.x * s4.x + a.y * s4.y + a.z * s4.z + a.w * s4.w;
            pd[mf] += a.x * d4.x + a.y * d4.y + a.z * d4.z + a.w * d4.w;
        }
    }
#pragma unroll
    for (int off = 16; off <= 32; off <<= 1) {
#pragma unroll
        for (int mf = 0; mf < 8; ++mf) {
            ps[mf] += __shfl_xor(ps[mf], off);
            pd[mf] += __shfl_xor(pd[mf], off);
        }
    }
    if (lk == 0) {
#pragma unroll
        for (int mf = 0; mf < 8; ++mf) {
            reda[w][mf * 16 + lm] = ps[mf];
            redb[w][mf * 16 + lm] = pd[mf];
        }
    }
    __syncthreads();
    if (tid < 128) {
        const int row = i0 + tid;
        if (row < BN_TOTAL) {
            const float a = reda[0][tid] + reda[1][tid] + reda[2][tid] + reda[3][tid];
            const float b = redb[0][tid] + redb[1][tid] + redb[2][tid] + redb[3][tid];
            AS[row * 4 + (j0 >> 7)] = a;
            AD[row * 4 + (j0 >> 7)] = b;
        }
    }
}

__device__ __forceinline__ int decode_src(int eid, const int* __restrict__ edge0) {
    if (eid < BE) { int b = eid / E_EDGES; return edge0[eid - b * E_EDGES] + b * N_NODES; }
    return eid - BE;
}

// ------- per-node ONLINE-softmax attention + aggregate (one wave / node), bf16 wh -------
__global__ __launch_bounds__(256) void gat_aggregate(const unsigned short* __restrict__ whb,
                                                     const float* __restrict__ AS, const float* __restrict__ AD,
                                                     const int* __restrict__ offs, const int* __restrict__ esort,
                                                     const int* __restrict__ edge0, const float* __restrict__ bias,
                                                     float* __restrict__ outf,
                                                     const float* __restrict__ fcw, const float* __restrict__ fcb,
                                                     float* __restrict__ out6) {
    const int lane = threadIdx.x & 63;
    const int bid = blockIdx.x;
    const int d = (bid & 7) * N_NODES + (bid >> 3) * 4 + (threadIdx.x >> 6);
    const int e0 = offs[d], e1 = offs[d + 1];
    const fx4 ad4 = *(const fx4*)&AD[d * 4];
    float mx0 = -1e30f, mx1 = -1e30f, mx2 = -1e30f, mx3 = -1e30f;
    float den0 = 0.f, den1 = 0.f, den2 = 0.f, den3 = 0.f;
    float acc[8] = {0.f, 0.f, 0.f, 0.f, 0.f, 0.f, 0.f, 0.f};
    for (int e = e0; e < e1; ++e) {
        const int src = decode_src(esort[e], edge0);
        const fx4 as4 = *(const fx4*)&AS[src * 4];
        float v0 = as4.x + ad4.x; v0 = v0 > 0.f ? v0 : 0.2f * v0;
        float v1 = as4.y + ad4.y; v1 = v1 > 0.f ? v1 : 0.2f * v1;
        float v2 = as4.z + ad4.z; v2 = v2 > 0.f ? v2 : 0.2f * v2;
        float v3 = as4.w + ad4.w; v3 = v3 > 0.f ? v3 : 0.2f * v3;
        const float n0 = fmaxf(mx0, v0), n1 = fmaxf(mx1, v1), n2 = fmaxf(mx2, v2), n3 = fmaxf(mx3, v3);
        const float c0 = __expf(mx0 - n0), c1 = __expf(mx1 - n1), c2 = __expf(mx2 - n2), c3 = __expf(mx3 - n3);
        const float ex0 = __expf(v0 - n0), ex1 = __expf(v1 - n1), ex2 = __expf(v2 - n2), ex3 = __expf(v3 - n3);
        mx0 = n0; mx1 = n1; mx2 = n2; mx3 = n3;
        den0 = den0 * c0 + ex0; den1 = den1 * c1 + ex1;
        den2 = den2 * c2 + ex2; den3 = den3 * c3 + ex3;
        const unsigned short* wr = whb + (size_t)src * 512;
        acc[0] = acc[0] * c0 + ex0 * bfu(wr[lane]);        acc[1] = acc[1] * c0 + ex0 * bfu(wr[64 + lane]);
        acc[2] = acc[2] * c1 + ex1 * bfu(wr[128 + lane]);  acc[3] = acc[3] * c1 + ex1 * bfu(wr[192 + lane]);
        acc[4] = acc[4] * c2 + ex2 * bfu(wr[256 + lane]);  acc[5] = acc[5] * c2 + ex2 * bfu(wr[320 + lane]);
        acc[6] = acc[6] * c3 + ex3 * bfu(wr[384 + lane]);  acc[7] = acc[7] * c3 + ex3 * bfu(wr[448 + lane]);
    }
    den0 += 1e-16f; den1 += 1e-16f; den2 += 1e-16f; den3 += 1e-16f;
    const float o0r = 0.25f * (acc[0] / den0 + acc[2] / den1 + acc[4] / den2 + acc[6] / den3) + bias[lane];
    const float o1r = 0.25f * (acc[1] / den0 + acc[3] / den1 + acc[5] / den2 + acc[7] / den3) + bias[64 + lane];
    const float o0 = fmaxf(o0r, 0.f);
    const float o1 = fmaxf(o1r, 0.f);
    if (fcw == nullptr) {
        outf[(size_t)d * 128 + lane] = o0;
        outf[(size_t)d * 128 + 64 + lane] = o1;
    } else {
        float p[6];
#pragma unroll
        for (int m = 0; m < 6; ++m) p[m] = o0 * fcw[m * 128 + lane] + o1 * fcw[m * 128 + 64 + lane];
#pragma unroll
        for (int off = 32; off > 0; off >>= 1) {
#pragma unroll
            for (int m = 0; m < 6; ++m) p[m] += __shfl_down(p[m], off);
        }
        if (lane == 0) {
#pragma unroll
            for (int m = 0; m < 6; ++m) out6[(size_t)d * 6 + m] = p[m] + fcb[m];
        }
    }
}

extern "C" void kernel_launch(void* const* d_in, const int* in_sizes, int n_in,
                              void* d_out, int out_size, void* d_ws, size_t ws_size,
                              hipStream_t stream) {
    const float* x = (const float*)d_in[0];
    const float* wih0 = (const float*)d_in[1];
    const float* whh0 = (const float*)d_in[2];
    const float* bih0 = (const float*)d_in[3];
    const float* bhh0 = (const float*)d_in[4];
    const float* wih1 = (const float*)d_in[5];
    const float* whh1 = (const float*)d_in[6];
    const float* bih1 = (const float*)d_in[7];
    const float* bhh1 = (const float*)d_in[8];
    const float* g1w = (const float*)d_in[9];
    const float* g1as = (const float*)d_in[10];
    const float* g1ad = (const float*)d_in[11];
    const float* g1b = (const float*)d_in[12];
    const float* g2w = (const float*)d_in[13];
    const float* g2as = (const float*)d_in[14];
    const float* g2ad = (const float*)d_in[15];
    const float* g2b = (const float*)d_in[16];
    const float* fcw = (const float*)d_in[17];
    const float* fcb = (const float*)d_in[18];
    const int* eidx = (const int*)d_in[19];
    const int* edge0 = eidx;
    const int* edge1 = eidx + E_EDGES;

    char* ws = (char*)d_ws;
    float* H0 = (float*)ws;                               // 40000*128 f32
    float* H1 = (float*)(ws + 20480000);                  // 40000*128 f32
    unsigned short* WHB = (unsigned short*)(ws + 40960000); // 40000*512 bf16 (41 MB)
    float* AS = (float*)(ws + 122880000);                 // 40000*4 f32
    float* AD = (float*)(ws + 123520000);                 // 40000*4 f32
    short* PK = (short*)(ws + 124160000);                 // 290816 bf16 packed weights
    int* OFFS = (int*)(ws + 124765184);                   // 40001 int
    int* CURS = (int*)(ws + 124925248);                   // 40000 int (also cnt)
    int* ESORT = (int*)(ws + 125085248);                  // 680000 int

    hipMemsetAsync(CURS, 0, BN_TOTAL * sizeof(int), stream);
    pack_w<<<1136, 256, 0, stream>>>(wih0, whh0, wih1, whh1, g1w, g2w, PK);
    csr_count<<<(NE + 255) / 256, 256, 0, stream>>>(edge1, CURS);
    csr_scan<<<1, 1024, 0, stream>>>(CURS, OFFS, CURS);
    csr_fill<<<(NE + 255) / 256, 256, 0, stream>>>(edge1, CURS, ESORT);

    gru_mfma<<<625, 512, 0, stream>>>(x, PK, bih0, bhh0, bih1, bhh1, H0);

    dim3 gg(313, 4);
    gat_gemm<<<gg, 256, 0, stream>>>(H0, PK + 159744, g1as, g1ad, WHB, AS, AD);
    gat_aggregate<<<10000, 256, 0, stream>>>(WHB, AS, AD, OFFS, ESORT, edge0, g1b, H1,
                                             nullptr, nullptr, nullptr);

    gat_gemm<<<gg, 256, 0, stream>>>(H1, PK + 225280, g2as, g2ad, WHB, AS, AD);
    gat_aggregate<<<10000, 256, 0, stream>>>(WHB, AS, AD, OFFS, ESORT, edge0, g2b, nullptr,
                                             fcw, fcb, (float*)d_out);
}

// Round 10
// 1047.495 us; speedup vs baseline: 1.3301x; 1.3301x over previous
//
#include <hip/hip_runtime.h>
#include <math.h>

#define T_STEPS 24
#define F_IN 10
#define HDIM 128
#define E_EDGES 80000
#define B_BATCH 8
#define N_NODES 5000
#define BN_TOTAL 40000
#define BE 640000
#define NE 680000

typedef __attribute__((ext_vector_type(8))) short s16x8;
typedef __attribute__((ext_vector_type(4))) short s16x4;
typedef __attribute__((ext_vector_type(4))) float fx4;
typedef __attribute__((ext_vector_type(2))) float fx2;
typedef __attribute__((ext_vector_type(4))) unsigned int ux4;
typedef __attribute__((ext_vector_type(2))) unsigned int ux2;

__device__ __forceinline__ float rcpf_(float v) { return __builtin_amdgcn_rcpf(v); }
__device__ __forceinline__ float sigmoidf_(float v) { return rcpf_(1.f + __expf(-v)); }
__device__ __forceinline__ float tanhf_(float v) { float e = __expf(2.f * v); return 1.f - 2.f * rcpf_(e + 1.f); }

__device__ __forceinline__ short f2b(float f) {
    unsigned u = __float_as_uint(f);
    unsigned r = (u + 0x7fffu + ((u >> 16) & 1u)) >> 16;
    return (short)r;
}
__device__ __forceinline__ unsigned int pkbf(float a, float b) {
    unsigned int r;
    asm("v_cvt_pk_bf16_f32 %0, %1, %2" : "=v"(r) : "v"(a), "v"(b));
    return r;
}
__device__ __forceinline__ float bfu(unsigned short u) {
    return __uint_as_float(((unsigned)u) << 16);
}

#define VMW0 asm volatile("s_waitcnt vmcnt(0)" ::: "memory")

// ---------------- pack weights into MFMA A-fragment order (bf16), nf-major ----------------
// shorts: [0,49152) hh0 ; [49152,98304) hh1 ; [98304,147456) ih1 ; [147456,159744) ih0(K pad 10->32)
//         [159744,225280) g1w ; [225280,290816) g2w
__global__ void pack_w(const float* __restrict__ wih0, const float* __restrict__ whh0,
                       const float* __restrict__ wih1, const float* __restrict__ whh1,
                       const float* __restrict__ g1w, const float* __restrict__ g2w,
                       short* __restrict__ pk) {
    int id = blockIdx.x * 256 + threadIdx.x;
    if (id >= 290816) return;
    if (id < 147456) {
        int mat = id / 49152, r = id % 49152;
        int nf = r / 2048, r2 = r % 2048, kf = r2 / 512, r3 = r2 % 512, lane = r3 / 8, j = r3 % 8;
        int n = nf * 16 + (lane & 15), k = kf * 32 + (lane >> 4) * 8 + j;
        const float* src = (mat == 0) ? whh0 : (mat == 1) ? whh1 : wih1;
        pk[id] = f2b(src[n * 128 + k]);
    } else if (id < 159744) {
        int r = id - 147456;
        int nf = r / 512, r2 = r % 512, lane = r2 / 8, j = r2 % 8;
        int n = nf * 16 + (lane & 15), k = (lane >> 4) * 8 + j;
        pk[id] = (k < F_IN) ? f2b(wih0[n * F_IN + k]) : (short)0;
    } else {
        const float* src = (id < 225280) ? g1w : g2w;
        int r = (id < 225280) ? (id - 159744) : (id - 225280);
        int nf = r / 2048, r2 = r % 2048, kf = r2 / 512, r3 = r2 % 512, lane = r3 / 8, j = r3 % 8;
        int n = nf * 16 + (lane & 15), k = kf * 32 + (lane >> 4) * 8 + j;
        pk[id] = f2b(src[n * 128 + k]);
    }
}

// ---------------- fused 2-layer GRU; 64 seqs/block (R8 structure: hh in regs, ih in LDS) ----------------
__global__ __launch_bounds__(512, 1) void gru_mfma(
    const float* __restrict__ x, const short* __restrict__ pk,
    const float* __restrict__ bih0, const float* __restrict__ bhh0,
    const float* __restrict__ bih1, const float* __restrict__ bhh1,
    float* __restrict__ temporal) {
    __shared__ __align__(16) short h1b[64 * 128];     // 16 KB
    __shared__ __align__(16) short h2b[64 * 128];     // 16 KB
    __shared__ __align__(16) short ih1s[49152];       // 96 KB
    __shared__ __align__(16) short ih0s[12288];       // 24 KB
    __shared__ __align__(16) float blds[2][4][128];   // 4 KB
    const int tid = threadIdx.x;
    const int w = tid >> 6, l = tid & 63;
    const int lm = l & 15, lk = l >> 4;
    const int jb = w * 16 + lk * 4;
    const long sb = (long)blockIdx.x * 64;

    {
        const char* src1 = (const char*)(pk + 98304);
#pragma unroll
        for (int r = 0; r < 12; ++r) {
            const int off = (w * 12 + r) * 1024;
            __builtin_amdgcn_global_load_lds(
                (const __attribute__((address_space(1))) unsigned int*)(src1 + off + l * 16),
                (__attribute__((address_space(3))) unsigned int*)((char*)ih1s + off), 16, 0, 0);
        }
        const char* src0 = (const char*)(pk + 147456);
#pragma unroll
        for (int r = 0; r < 3; ++r) {
            const int off = (w * 3 + r) * 1024;
            __builtin_amdgcn_global_load_lds(
                (const __attribute__((address_space(1))) unsigned int*)(src0 + off + l * 16),
                (__attribute__((address_space(3))) unsigned int*)((char*)ih0s + off), 16, 0, 0);
        }
    }
    if (tid < 128) {
        const int j = tid;
        blds[0][0][j] = bih0[j] + bhh0[j];
        blds[0][1][j] = bih0[128 + j] + bhh0[128 + j];
        blds[0][2][j] = bhh0[256 + j];
        blds[0][3][j] = bih0[256 + j];
    } else if (tid < 256) {
        const int j = tid - 128;
        blds[1][0][j] = bih1[j] + bhh1[j];
        blds[1][1][j] = bih1[128 + j] + bhh1[128 + j];
        blds[1][2][j] = bhh1[256 + j];
        blds[1][3][j] = bih1[256 + j];
    }
    for (int i = tid; i < 64 * 128; i += 512) { h1b[i] = 0; h2b[i] = 0; }

    // ---- recurrent weights resident in registers ----
    s16x8 whh0r[3][4], whh1r[3][4];
#pragma unroll
    for (int g = 0; g < 3; ++g)
#pragma unroll
        for (int kf = 0; kf < 4; ++kf) {
            const int idx = ((((g * 8 + w) * 4) + kf) * 64 + l) * 8;
            whh0r[g][kf] = *(const s16x8*)&pk[idx];
            whh1r[g][kf] = *(const s16x8*)&pk[49152 + idx];
        }

    fx4 h1s[4], h2s[4];
#pragma unroll
    for (int mf = 0; mf < 4; ++mf) { h1s[mf] = (fx4)(0.f); h2s[mf] = (fx4)(0.f); }

    VMW0;
    __syncthreads();

    for (int tt = 0; tt < T_STEPS; ++tt) {
        // ---- x loads, converted to bf16 immediately ----
        ux4 xu[4];
#pragma unroll
        for (int mf = 0; mf < 4; ++mf) {
            fx2 a0 = (fx2)(0.f), a1 = (fx2)(0.f), a2 = (fx2)(0.f), a3 = (fx2)(0.f);
            const float* xr = x + (sb + mf * 16 + lm) * (T_STEPS * F_IN) + tt * F_IN;
            if (lk == 0) {
                a0 = *(const fx2*)(xr);     a1 = *(const fx2*)(xr + 2);
                a2 = *(const fx2*)(xr + 4); a3 = *(const fx2*)(xr + 6);
            } else if (lk == 1) {
                a0 = *(const fx2*)(xr + 8);
            }
            ux4 t = { pkbf(a0.x, a0.y), pkbf(a1.x, a1.y), pkbf(a2.x, a2.y), pkbf(a3.x, a3.y) };
            xu[mf] = t;
        }
        fx4 acc[4][4];
#pragma unroll
        for (int p = 0; p < 4; ++p) {
            const fx4 bv = *(const fx4*)&blds[0][p][jb];
#pragma unroll
            for (int mf = 0; mf < 4; ++mf) acc[p][mf] = bv;
        }
        // ===== layer 0: hh0 (B = h1 old), parts r,z,nh =====
#pragma unroll
        for (int kf = 0; kf < 4; ++kf) {
            s16x8 bfr[4];
#pragma unroll
            for (int mf = 0; mf < 4; ++mf) {
                const int m = mf * 16 + lm;
                const int slot = (kf * 4 + lk) ^ (m & 7);
                bfr[mf] = *(const s16x8*)&h1b[m * 128 + slot * 8];
            }
#pragma unroll
            for (int g = 0; g < 3; ++g) {
                const int part = (g == 2) ? 2 : g;
#pragma unroll
                for (int mf = 0; mf < 4; ++mf)
                    acc[part][mf] = __builtin_amdgcn_mfma_f32_16x16x32_bf16(whh0r[g][kf], bfr[mf], acc[part][mf], 0, 0, 0);
            }
        }
        // ---- ih0 (A LDS-resident, B = x frags), parts r,z,ni ----
#pragma unroll
        for (int g = 0; g < 3; ++g) {
            const int part = (g == 2) ? 3 : g;
            const s16x8 af = *(const s16x8*)&ih0s[((g * 8 + w) * 64 + l) * 8];
#pragma unroll
            for (int mf = 0; mf < 4; ++mf)
                acc[part][mf] = __builtin_amdgcn_mfma_f32_16x16x32_bf16(af, __builtin_bit_cast(s16x8, xu[mf]), acc[part][mf], 0, 0, 0);
        }
        // ---- elementwise layer 0 -> h1 (fp32 state), rcp-based activations ----
        ux2 w1[4];
#pragma unroll
        for (int mf = 0; mf < 4; ++mf) {
#pragma unroll
            for (int rg = 0; rg < 4; ++rg) {
                const float r = sigmoidf_(acc[0][mf][rg]);
                const float z = sigmoidf_(acc[1][mf][rg]);
                const float n = tanhf_(acc[3][mf][rg] + r * acc[2][mf][rg]);
                h1s[mf][rg] = n + z * (h1s[mf][rg] - n);
            }
            ux2 q = { pkbf(h1s[mf][0], h1s[mf][1]), pkbf(h1s[mf][2], h1s[mf][3]) };
            w1[mf] = q;
        }
        // ===== layer 1: hh1 (B = h2 old), parts r,z,nh =====
#pragma unroll
        for (int p = 0; p < 4; ++p) {
            const fx4 bv = *(const fx4*)&blds[1][p][jb];
#pragma unroll
            for (int mf = 0; mf < 4; ++mf) acc[p][mf] = bv;
        }
#pragma unroll
        for (int kf = 0; kf < 4; ++kf) {
            s16x8 bfr[4];
#pragma unroll
            for (int mf = 0; mf < 4; ++mf) {
                const int m = mf * 16 + lm;
                const int slot = (kf * 4 + lk) ^ (m & 7);
                bfr[mf] = *(const s16x8*)&h2b[m * 128 + slot * 8];
            }
#pragma unroll
            for (int g = 0; g < 3; ++g) {
                const int part = (g == 2) ? 2 : g;
#pragma unroll
                for (int mf = 0; mf < 4; ++mf)
                    acc[part][mf] = __builtin_amdgcn_mfma_f32_16x16x32_bf16(whh1r[g][kf], bfr[mf], acc[part][mf], 0, 0, 0);
            }
        }
        __syncthreads();   // all reads of h1b(old)/h2b(old) complete
#pragma unroll
        for (int mf = 0; mf < 4; ++mf) {
            const int m = mf * 16 + lm;
            const int slot = (jb >> 3) ^ (m & 7);
            *(ux2*)&h1b[m * 128 + slot * 8 + (jb & 7)] = w1[mf];
        }
        __syncthreads();   // h1 new visible
        // ===== layer 1: ih1 (A LDS-resident, B = h1 new), parts r,z,ni =====
#pragma unroll
        for (int kf = 0; kf < 4; ++kf) {
            s16x8 bfr[4];
#pragma unroll
            for (int mf = 0; mf < 4; ++mf) {
                const int m = mf * 16 + lm;
                const int slot = (kf * 4 + lk) ^ (m & 7);
                bfr[mf] = *(const s16x8*)&h1b[m * 128 + slot * 8];
            }
#pragma unroll
            for (int g = 0; g < 3; ++g) {
                const int part = (g == 2) ? 3 : g;
                const s16x8 af = *(const s16x8*)&ih1s[((((g * 8 + w) * 4) + kf) * 64 + l) * 8];
#pragma unroll
                for (int mf = 0; mf < 4; ++mf)
                    acc[part][mf] = __builtin_amdgcn_mfma_f32_16x16x32_bf16(af, bfr[mf], acc[part][mf], 0, 0, 0);
            }
        }
        // ---- elementwise layer 1 -> h2, publish ----
#pragma unroll
        for (int mf = 0; mf < 4; ++mf) {
#pragma unroll
            for (int rg = 0; rg < 4; ++rg) {
                const float r = sigmoidf_(acc[0][mf][rg]);
                const float z = sigmoidf_(acc[1][mf][rg]);
                const float n = tanhf_(acc[3][mf][rg] + r * acc[2][mf][rg]);
                h2s[mf][rg] = n + z * (h2s[mf][rg] - n);
            }
            const int m = mf * 16 + lm;
            const int slot = (jb >> 3) ^ (m & 7);
            ux2 q = { pkbf(h2s[mf][0], h2s[mf][1]), pkbf(h2s[mf][2], h2s[mf][3]) };
            *(ux2*)&h2b[m * 128 + slot * 8 + (jb & 7)] = q;
        }
        __syncthreads();   // h2 new visible for next step
    }
#pragma unroll
    for (int mf = 0; mf < 4; ++mf) {
        const long m = sb + mf * 16 + lm;
        *(fx4*)&temporal[m * 128 + jb] = h2s[mf];
    }
}

// ---------------- CSR build ----------------
__global__ void csr_count(const int* __restrict__ edge1, int* __restrict__ cnt) {
    int e = blockIdx.x * 256 + threadIdx.x;
    if (e >= NE) return;
    int d;
    if (e < BE) { int b = e / E_EDGES; d = edge1[e - b * E_EDGES] + b * N_NODES; }
    else d = e - BE;
    atomicAdd(&cnt[d], 1);
}

__global__ void csr_scan(const int* cnt, int* offs, int* curs) {
    __shared__ int part[1024];
    const int t = threadIdx.x;
    const int base = t * 40;
    int end = base + 40; if (end > BN_TOTAL) end = BN_TOTAL;
    int s = 0;
    for (int i = base; i < end; ++i) s += cnt[i];
    part[t] = s;
    __syncthreads();
    for (int off = 1; off < 1024; off <<= 1) {
        int v = (t >= off) ? part[t - off] : 0;
        __syncthreads();
        part[t] += v;
        __syncthreads();
    }
    int run = part[t] - s;
    for (int i = base; i < end; ++i) {
        int c = cnt[i];
        offs[i] = run; curs[i] = run; run += c;
    }
    if (t == 1023) offs[BN_TOTAL] = NE;
}

__global__ void csr_fill(const int* __restrict__ edge1, int* __restrict__ curs, int* __restrict__ esort) {
    int e = blockIdx.x * 256 + threadIdx.x;
    if (e >= NE) return;
    int d;
    if (e < BE) { int b = e / E_EDGES; d = edge1[e - b * E_EDGES] + b * N_NODES; }
    else d = e - BE;
    int pos = atomicAdd(&curs[d], 1);
    esort[pos] = e;
}

// ------- GAT: wh = feat @ W.T via MFMA (128 rows x one head per block), bf16 out -------
__global__ __launch_bounds__(256, 2) void gat_gemm(const float* __restrict__ feat,
                                                   const short* __restrict__ pkg,
                                                   const float* __restrict__ asrc,
                                                   const float* __restrict__ adst,
                                                   unsigned short* __restrict__ whb,
                                                   float* __restrict__ AS, float* __restrict__ AD) {
    __shared__ __align__(16) short fb[128 * 128];   // 32 KB bf16, XOR-swizzled
    __shared__ float reda[4][128];
    __shared__ float redb[4][128];
    const int tid = threadIdx.x;
    const int w = tid >> 6, l = tid & 63;
    const int lm = l & 15, lk = l >> 4;
    const int i0 = blockIdx.x * 128;
    const int j0 = blockIdx.y * 128;     // == head*128
#pragma unroll
    for (int it = 0; it < 16; ++it) {
        const int idx = it * 256 + tid;
        const int r = idx >> 5, kq = idx & 31;
        fx4 v = (fx4)(0.f);
        const int row = i0 + r;
        if (row < BN_TOTAL) v = *(const fx4*)&feat[(size_t)row * 128 + kq * 4];
        const int slot = (kq >> 1) ^ (r & 7);
        ux2 pv = { pkbf(v.x, v.y), pkbf(v.z, v.w) };
        *(ux2*)&fb[r * 128 + slot * 8 + (kq & 1) * 4] = pv;
    }
    __syncthreads();
    fx4 acc[2][8];
#pragma unroll
    for (int jf = 0; jf < 2; ++jf)
#pragma unroll
        for (int mf = 0; mf < 8; ++mf) acc[jf][mf] = (fx4)(0.f);
#pragma unroll
    for (int kf = 0; kf < 4; ++kf) {
        s16x8 bfr[8];
#pragma unroll
        for (int mf = 0; mf < 8; ++mf) {
            const int m = mf * 16 + lm;
            const int slot = (kf * 4 + lk) ^ (m & 7);
            bfr[mf] = *(const s16x8*)&fb[m * 128 + slot * 8];
        }
#pragma unroll
        for (int jf = 0; jf < 2; ++jf) {
            const int nf = (j0 >> 4) + w * 2 + jf;
            const s16x8 af = *(const s16x8*)&pkg[((nf * 4 + kf) * 64 + l) * 8];
#pragma unroll
            for (int mf = 0; mf < 8; ++mf)
                acc[jf][mf] = __builtin_amdgcn_mfma_f32_16x16x32_bf16(af, bfr[mf], acc[jf][mf], 0, 0, 0);
        }
    }
    // ---- write wh (bf16) + fused alpha partials (fp32) ----
    float ps[8], pd[8];
#pragma unroll
    for (int mf = 0; mf < 8; ++mf) { ps[mf] = 0.f; pd[mf] = 0.f; }
#pragma unroll
    for (int jf = 0; jf < 2; ++jf) {
        const int cb = w * 32 + jf * 16 + lk * 4;
        const fx4 s4 = *(const fx4*)&asrc[j0 + cb];
        const fx4 d4 = *(const fx4*)&adst[j0 + cb];
        const int nb = j0 + cb;
#pragma unroll
        for (int mf = 0; mf < 8; ++mf) {
            const int m = i0 + mf * 16 + lm;
            const fx4 a = acc[jf][mf];
            if (m < BN_TOTAL) {
                ux2 pv = { pkbf(a.x, a.y), pkbf(a.z, a.w) };
                *(ux2*)&whb[(size_t)m * 512 + nb] = pv;
            }
            ps[mf] += a.x * s4.x + a.y * s4.y + a.z * s4.z + a.w * s4.w;
            pd[mf] += a.x * d4.x + a.y * d4.y + a.z * d4.z + a.w * d4.w;
        }
    }
#pragma unroll
    for (int off = 16; off <= 32; off <<= 1) {
#pragma unroll
        for (int mf = 0; mf < 8; ++mf) {
            ps[mf] += __shfl_xor(ps[mf], off);
            pd[mf] += __shfl_xor(pd[mf], off);
        }
    }
    if (lk == 0) {
#pragma unroll
        for (int mf = 0; mf < 8; ++mf) {
            reda[w][mf * 16 + lm] = ps[mf];
            redb[w][mf * 16 + lm] = pd[mf];
        }
    }
    __syncthreads();
    if (tid < 128) {
        const int row = i0 + tid;
        if (row < BN_TOTAL) {
            const float a = reda[0][tid] + reda[1][tid] + reda[2][tid] + reda[3][tid];
            const float b = redb[0][tid] + redb[1][tid] + redb[2][tid] + redb[3][tid];
            AS[row * 4 + (j0 >> 7)] = a;
            AD[row * 4 + (j0 >> 7)] = b;
        }
    }
}

__device__ __forceinline__ int decode_src(int eid, const int* __restrict__ edge0) {
    if (eid < BE) { int b = eid / E_EDGES; return edge0[eid - b * E_EDGES] + b * N_NODES; }
    return eid - BE;
}

// ------- per-node ONLINE-softmax attention + aggregate; paired-u32 gather -------
// lane owns cols {2l, 2l+1} of each head.
__global__ __launch_bounds__(256) void gat_aggregate(const unsigned short* __restrict__ whb,
                                                     const float* __restrict__ AS, const float* __restrict__ AD,
                                                     const int* __restrict__ offs, const int* __restrict__ esort,
                                                     const int* __restrict__ edge0, const float* __restrict__ bias,
                                                     float* __restrict__ outf,
                                                     const float* __restrict__ fcw, const float* __restrict__ fcb,
                                                     float* __restrict__ out6) {
    const int lane = threadIdx.x & 63;
    const int bid = blockIdx.x;
    const int d = (bid & 7) * N_NODES + (bid >> 3) * 4 + (threadIdx.x >> 6);
    const int e0 = offs[d], e1 = offs[d + 1];
    const fx4 ad4 = *(const fx4*)&AD[d * 4];
    float mx0 = -1e30f, mx1 = -1e30f, mx2 = -1e30f, mx3 = -1e30f;
    float den0 = 0.f, den1 = 0.f, den2 = 0.f, den3 = 0.f;
    float acc[8] = {0.f, 0.f, 0.f, 0.f, 0.f, 0.f, 0.f, 0.f};
    for (int e = e0; e < e1; ++e) {
        const int src = decode_src(esort[e], edge0);
        const fx4 as4 = *(const fx4*)&AS[src * 4];
        float v0 = as4.x + ad4.x; v0 = v0 > 0.f ? v0 : 0.2f * v0;
        float v1 = as4.y + ad4.y; v1 = v1 > 0.f ? v1 : 0.2f * v1;
        float v2 = as4.z + ad4.z; v2 = v2 > 0.f ? v2 : 0.2f * v2;
        float v3 = as4.w + ad4.w; v3 = v3 > 0.f ? v3 : 0.2f * v3;
        const float n0 = fmaxf(mx0, v0), n1 = fmaxf(mx1, v1), n2 = fmaxf(mx2, v2), n3 = fmaxf(mx3, v3);
        const float c0 = __expf(mx0 - n0), c1 = __expf(mx1 - n1), c2 = __expf(mx2 - n2), c3 = __expf(mx3 - n3);
        const float ex0 = __expf(v0 - n0), ex1 = __expf(v1 - n1), ex2 = __expf(v2 - n2), ex3 = __expf(v3 - n3);
        mx0 = n0; mx1 = n1; mx2 = n2; mx3 = n3;
        den0 = den0 * c0 + ex0; den1 = den1 * c1 + ex1;
        den2 = den2 * c2 + ex2; den3 = den3 * c3 + ex3;
        const unsigned int* wr = (const unsigned int*)(whb + (size_t)src * 512);
        const unsigned int u0 = wr[lane];         // head0 cols 2l,2l+1
        const unsigned int u1 = wr[64 + lane];    // head1
        const unsigned int u2 = wr[128 + lane];   // head2
        const unsigned int u3 = wr[192 + lane];   // head3
        acc[0] = acc[0] * c0 + ex0 * bfu((unsigned short)u0);
        acc[1] = acc[1] * c0 + ex0 * bfu((unsigned short)(u0 >> 16));
        acc[2] = acc[2] * c1 + ex1 * bfu((unsigned short)u1);
        acc[3] = acc[3] * c1 + ex1 * bfu((unsigned short)(u1 >> 16));
        acc[4] = acc[4] * c2 + ex2 * bfu((unsigned short)u2);
        acc[5] = acc[5] * c2 + ex2 * bfu((unsigned short)(u2 >> 16));
        acc[6] = acc[6] * c3 + ex3 * bfu((unsigned short)u3);
        acc[7] = acc[7] * c3 + ex3 * bfu((unsigned short)(u3 >> 16));
    }
    const float i0v = rcpf_(den0 + 1e-16f), i1v = rcpf_(den1 + 1e-16f);
    const float i2v = rcpf_(den2 + 1e-16f), i3v = rcpf_(den3 + 1e-16f);
    const int c0i = 2 * lane, c1i = 2 * lane + 1;
    const float o0r = 0.25f * (acc[0] * i0v + acc[2] * i1v + acc[4] * i2v + acc[6] * i3v) + bias[c0i];
    const float o1r = 0.25f * (acc[1] * i0v + acc[3] * i1v + acc[5] * i2v + acc[7] * i3v) + bias[c1i];
    const float o0 = fmaxf(o0r, 0.f);
    const float o1 = fmaxf(o1r, 0.f);
    if (fcw == nullptr) {
        fx2 ov = { o0, o1 };
        *(fx2*)&outf[(size_t)d * 128 + c0i] = ov;
    } else {
        float p[6];
#pragma unroll
        for (int m = 0; m < 6; ++m) p[m] = o0 * fcw[m * 128 + c0i] + o1 * fcw[m * 128 + c1i];
#pragma unroll
        for (int off = 32; off > 0; off >>= 1) {
#pragma unroll
            for (int m = 0; m < 6; ++m) p[m] += __shfl_down(p[m], off);
        }
        if (lane == 0) {
#pragma unroll
            for (int m = 0; m < 6; ++m) out6[(size_t)d * 6 + m] = p[m] + fcb[m];
        }
    }
}

extern "C" void kernel_launch(void* const* d_in, const int* in_sizes, int n_in,
                              void* d_out, int out_size, void* d_ws, size_t ws_size,
                              hipStream_t stream) {
    const float* x = (const float*)d_in[0];
    const float* wih0 = (const float*)d_in[1];
    const float* whh0 = (const float*)d_in[2];
    const float* bih0 = (const float*)d_in[3];
    const float* bhh0 = (const float*)d_in[4];
    const float* wih1 = (const float*)d_in[5];
    const float* whh1 = (const float*)d_in[6];
    const float* bih1 = (const float*)d_in[7];
    const float* bhh1 = (const float*)d_in[8];
    const float* g1w = (const float*)d_in[9];
    const float* g1as = (const float*)d_in[10];
    const float* g1ad = (const float*)d_in[11];
    const float* g1b = (const float*)d_in[12];
    const float* g2w = (const float*)d_in[13];
    const float* g2as = (const float*)d_in[14];
    const float* g2ad = (const float*)d_in[15];
    const float* g2b = (const float*)d_in[16];
    const float* fcw = (const float*)d_in[17];
    const float* fcb = (const float*)d_in[18];
    const int* eidx = (const int*)d_in[19];
    const int* edge0 = eidx;
    const int* edge1 = eidx + E_EDGES;

    char* ws = (char*)d_ws;
    float* H0 = (float*)ws;                               // 40000*128 f32
    float* H1 = (float*)(ws + 20480000);                  // 40000*128 f32
    unsigned short* WHB = (unsigned short*)(ws + 40960000); // 40000*512 bf16
    float* AS = (float*)(ws + 122880000);                 // 40000*4 f32
    float* AD = (float*)(ws + 123520000);                 // 40000*4 f32
    short* PK = (short*)(ws + 124160000);                 // 290816 bf16 packed weights
    int* OFFS = (int*)(ws + 124765184);                   // 40001 int
    int* CURS = (int*)(ws + 124925248);                   // 40000 int (also cnt)
    int* ESORT = (int*)(ws + 125085248);                  // 680000 int

    hipMemsetAsync(CURS, 0, BN_TOTAL * sizeof(int), stream);
    pack_w<<<1136, 256, 0, stream>>>(wih0, whh0, wih1, whh1, g1w, g2w, PK);
    csr_count<<<(NE + 255) / 256, 256, 0, stream>>>(edge1, CURS);
    csr_scan<<<1, 1024, 0, stream>>>(CURS, OFFS, CURS);
    csr_fill<<<(NE + 255) / 256, 256, 0, stream>>>(edge1, CURS, ESORT);

    gru_mfma<<<625, 512, 0, stream>>>(x, PK, bih0, bhh0, bih1, bhh1, H0);

    dim3 gg(313, 4);
    gat_gemm<<<gg, 256, 0, stream>>>(H0, PK + 159744, g1as, g1ad, WHB, AS, AD);
    gat_aggregate<<<10000, 256, 0, stream>>>(WHB, AS, AD, OFFS, ESORT, edge0, g1b, H1,
                                             nullptr, nullptr, nullptr);

    gat_gemm<<<gg, 256, 0, stream>>>(H1, PK + 225280, g2as, g2ad, WHB, AS, AD);
    gat_aggregate<<<10000, 256, 0, stream>>>(WHB, AS, AD, OFFS, ESORT, edge0, g2b, nullptr,
                                             fcw, fcb, (float*)d_out);
}